// Round 9
// baseline (349.326 us; speedup 1.0000x reference)
//
#include <hip/hip_runtime.h>
#include <hip/hip_fp16.h>

#define DIM 64

typedef __attribute__((ext_vector_type(2))) float floatx2;
typedef __attribute__((ext_vector_type(4))) float f32x4;
typedef __attribute__((ext_vector_type(8))) _Float16 f16x8;
typedef __attribute__((ext_vector_type(4))) _Float16 f16x4;

// ---------------- pass 0: zero deg + pooled output ----------------

__global__ __launch_bounds__(256) void k_zero(int* __restrict__ deg,
                                              float* __restrict__ out,
                                              int N, int GD) {
    int i = blockIdx.x * 256 + threadIdx.x;
    int stride = gridDim.x * 256;
    for (int j = i; j < N; j += stride) deg[j] = 0;
    for (int j = i; j < GD; j += stride) out[j] = 0.f;
}

// ---------------- pass 1: node degrees via global atomics ----------------

__global__ __launch_bounds__(256) void k_deg(const int* __restrict__ dst,
                                             int* __restrict__ deg, int E) {
    int i = blockIdx.x * 256 + threadIdx.x;
    int stride = gridDim.x * 256;
    for (int e = i; e < E; e += stride)
        atomicAdd(&deg[dst[e]], 1);
}

// ---------------- pass 2a: block-local exclusive scan of deg (4096/block, shfl) ----------------

__global__ __launch_bounds__(1024) void k_scanA2(const int* __restrict__ deg,
                                                 int* __restrict__ off,
                                                 int* __restrict__ bsums, int N) {
    __shared__ int ws[16];
    int tid = threadIdx.x;
    int j0 = blockIdx.x * 4096 + tid * 4;
    int v[4]; int sum = 0;
#pragma unroll
    for (int t = 0; t < 4; ++t) {
        int j = j0 + t;
        int x = (j < N) ? deg[j] : 0;
        v[t] = sum; sum += x;
    }
    int lane = tid & 63, wv = tid >> 6;
    int x = sum;
#pragma unroll
    for (int d = 1; d < 64; d <<= 1) {
        int t = __shfl_up(x, d);
        if (lane >= d) x += t;
    }
    if (lane == 63) ws[wv] = x;
    __syncthreads();
    int prefix = 0;
    for (int w = 0; w < wv; ++w) prefix += ws[w];
    int ex = prefix + x - sum;               // exclusive base for this thread's 4
#pragma unroll
    for (int t = 0; t < 4; ++t) {
        int j = j0 + t;
        if (j < N) off[j] = ex + v[t];
    }
    if (tid == 1023) bsums[blockIdx.x] = prefix + x;   // block total
}

// ---------------- pass 2b: add cross-block bases; emit off, cur, dinv, goff ----------------
// each block sums its <=32 predecessor bsums in-register (no separate scanB kernel).

__global__ __launch_bounds__(1024) void k_scanC(int* __restrict__ off,
                                                int* __restrict__ cur,
                                                const int* __restrict__ bsums,
                                                const int* __restrict__ deg,
                                                const int* __restrict__ batch,
                                                float* __restrict__ dinv,
                                                int* __restrict__ goff,
                                                int N, int G, int E) {
    int blk = blockIdx.x;
    int base = 0;
    for (int w = 0; w < blk; ++w) base += bsums[w];
    int j = blk * 4096 + threadIdx.x;
#pragma unroll
    for (int t = 0; t < 4; ++t, j += 1024) {
        if (j < N) {
            int o = off[j] + base;
            off[j] = o;
            cur[j] = o;
            dinv[j] = rsqrtf((float)(deg[j] + 1));   // +1 self-loop
            // fused gbound (batch sorted)
            int bb = batch[j];
            int prev = (j == 0) ? -1 : batch[j - 1];
            for (int g = prev + 1; g <= bb; ++g) goff[g] = j;
            if (j == N - 1) {
                off[N] = E;
                for (int g = bb + 1; g <= G; ++g) goff[g] = N;
            }
        }
    }
}

// ---------------- pass 3: direct CSR scatter via node-level atomic cursors ----------------

__global__ __launch_bounds__(256) void k_scatter(const int* __restrict__ src,
                                                 const int* __restrict__ dst,
                                                 int* __restrict__ cur,
                                                 int* __restrict__ csr, int E) {
    int i = blockIdx.x * 256 + threadIdx.x;
    int stride = gridDim.x * 256;
    for (int e = i; e < E; e += stride) {
        int d = dst[e];
        int pos = atomicAdd(&cur[d], 1);
        csr[pos] = src[e];
    }
}

// ---------------- skinny GEMM via MFMA: hs[row] = (X[row] @ W) * dinv[row], fp8 out ----------------
// Wave w computes the 16-row x 16-col tile at cols [16w,16w+16).
// k-map bijection: k = 32s + 8*(lane>>4) + elem, applied to BOTH A and B fragments.
// D layout (HW-verified): col = lane&15, row = 4*(lane>>4) + reg.

__global__ __launch_bounds__(256) void k_gemm(const float* __restrict__ X,
                                              const float* __restrict__ W,
                                              const float* __restrict__ dinv,
                                              unsigned int* __restrict__ Y8, int N) {
    __shared__ float Os[16 * 68];
    int tid = threadIdx.x;
    int lane = tid & 63, w = tid >> 6;
    int m = lane & 15, g = lane >> 4;
    int row0 = blockIdx.x * 16;
    int row = row0 + m;

    // B fragments from global W (row-major [k][n]); L1-hot
    f16x8 B0, B1;
    {
        int n = (w << 4) + m;
        const float* wp = W + (g << 3) * 64 + n;
#pragma unroll
        for (int j = 0; j < 8; ++j) B0[j] = (_Float16)wp[j * 64];
        wp += 32 * 64;
#pragma unroll
        for (int j = 0; j < 8; ++j) B1[j] = (_Float16)wp[j * 64];
    }
    // A fragments straight from global X
    f16x8 A0, A1;
    {
        float4 u0 = make_float4(0.f, 0.f, 0.f, 0.f), u1 = u0, u2 = u0, u3 = u0;
        if (row < N) {
            const float* xp = X + (size_t)row * DIM + (g << 3);
            u0 = *(const float4*)(xp);
            u1 = *(const float4*)(xp + 4);
            u2 = *(const float4*)(xp + 32);
            u3 = *(const float4*)(xp + 36);
        }
        A0[0] = (_Float16)u0.x; A0[1] = (_Float16)u0.y; A0[2] = (_Float16)u0.z; A0[3] = (_Float16)u0.w;
        A0[4] = (_Float16)u1.x; A0[5] = (_Float16)u1.y; A0[6] = (_Float16)u1.z; A0[7] = (_Float16)u1.w;
        A1[0] = (_Float16)u2.x; A1[1] = (_Float16)u2.y; A1[2] = (_Float16)u2.z; A1[3] = (_Float16)u2.w;
        A1[4] = (_Float16)u3.x; A1[5] = (_Float16)u3.y; A1[6] = (_Float16)u3.z; A1[7] = (_Float16)u3.w;
    }
    f32x4 acc = {0.f, 0.f, 0.f, 0.f};
    acc = __builtin_amdgcn_mfma_f32_16x16x32_f16(A0, B0, acc, 0, 0, 0);
    acc = __builtin_amdgcn_mfma_f32_16x16x32_f16(A1, B1, acc, 0, 0, 0);
#pragma unroll
    for (int j = 0; j < 4; ++j)
        Os[((g << 2) + j) * 68 + (w << 4) + m] = acc[j];
    __syncthreads();

    int r = tid >> 4, c = tid & 15;
    int orow = row0 + r;
    if (orow < N) {
        float4 o = *(const float4*)(Os + r * 68 + (c << 2));
        float s = dinv[orow];
        int p = 0;
        p = __builtin_amdgcn_cvt_pk_fp8_f32(o.x * s, o.y * s, p, false);
        p = __builtin_amdgcn_cvt_pk_fp8_f32(o.z * s, o.w * s, p, true);
        Y8[(size_t)orow * 16 + c] = (unsigned int)p;
    } else if (orow == N) {
        Y8[(size_t)orow * 16 + c] = 0u;   // +0 in e4m3 (gather pad row)
    }
}

// ---------------- gather core: 16-lane group per node, 16 edges / 16 loads in flight ----------------
// lane l owns cols 4l..4l+3 (one uint of the fp8 row). Padding slots read row N (zeros,
// single broadcast cacheline). All 16 loads issued before any conversion.

__device__ __forceinline__ float4 gather_rows(const unsigned int* __restrict__ hs8,
                                              const int* __restrict__ csr,
                                              int k0, int k1, int v, int l, int gw4,
                                              int N) {
    float4 a0, a1, a2, a3;
    {
        unsigned int u = hs8[(unsigned)((v << 4) | l)];    // self-loop term
        floatx2 f0 = __builtin_amdgcn_cvt_pk_f32_fp8((int)u, false);
        floatx2 f1 = __builtin_amdgcn_cvt_pk_f32_fp8((int)u, true);
        a0 = make_float4(f0.x, f0.y, f1.x, f1.y);
        a1 = make_float4(0.f, 0.f, 0.f, 0.f);
        a2 = make_float4(0.f, 0.f, 0.f, 0.f);
        a3 = make_float4(0.f, 0.f, 0.f, 0.f);
    }
    for (int kb = k0; kb < k1; kb += 16) {
        int rem = k1 - kb;
        int idx = (l < rem) ? csr[kb + l] : N;
        unsigned uu[16];
#pragma unroll
        for (int t = 0; t < 16; ++t) {
            int s = __shfl(idx, gw4 + t);
            uu[t] = hs8[(unsigned)((s << 4) | l)];
        }
#pragma unroll
        for (int t = 0; t < 16; t += 4) {
            floatx2 q0 = __builtin_amdgcn_cvt_pk_f32_fp8((int)uu[t + 0], false);
            floatx2 q1 = __builtin_amdgcn_cvt_pk_f32_fp8((int)uu[t + 0], true);
            floatx2 q2 = __builtin_amdgcn_cvt_pk_f32_fp8((int)uu[t + 1], false);
            floatx2 q3 = __builtin_amdgcn_cvt_pk_f32_fp8((int)uu[t + 1], true);
            floatx2 q4 = __builtin_amdgcn_cvt_pk_f32_fp8((int)uu[t + 2], false);
            floatx2 q5 = __builtin_amdgcn_cvt_pk_f32_fp8((int)uu[t + 2], true);
            floatx2 q6 = __builtin_amdgcn_cvt_pk_f32_fp8((int)uu[t + 3], false);
            floatx2 q7 = __builtin_amdgcn_cvt_pk_f32_fp8((int)uu[t + 3], true);
            a0.x += q0.x; a0.y += q0.y; a0.z += q1.x; a0.w += q1.y;
            a1.x += q2.x; a1.y += q2.y; a1.z += q3.x; a1.w += q3.y;
            a2.x += q4.x; a2.y += q4.y; a2.z += q5.x; a2.w += q5.y;
            a3.x += q6.x; a3.y += q6.y; a3.z += q7.x; a3.w += q7.y;
        }
    }
    return make_float4(a0.x + a1.x + a2.x + a3.x,
                       a0.y + a1.y + a2.y + a3.y,
                       a0.z + a1.z + a2.z + a3.z,
                       a0.w + a1.w + a2.w + a3.w);
}

// ---------------- fused gather + MFMA GEMM (layer 1 -> hs2 fp8 directly) ----------------
// block = 256 threads = 16 nodes. gathered row relu'd into fp16 LDS tile, MFMA vs W2
// fragments (built from global, no W LDS), fp32 epilogue transpose via Os, fp8 out.

__global__ __launch_bounds__(256) void k_gather_gemm(const unsigned int* __restrict__ hs8,
                                                     const int* __restrict__ csr,
                                                     const int* __restrict__ off,
                                                     const float* __restrict__ dinv,
                                                     const float* __restrict__ bias,
                                                     const float* __restrict__ W,
                                                     unsigned int* __restrict__ hs_out,
                                                     int N) {
    __shared__ _Float16 Xs[16 * 72];
    __shared__ float Os[16 * 68];
    int tid = threadIdx.x;
    int r = tid >> 4, l = tid & 15;
    int lane = tid & 63, w = tid >> 6;
    int m = lane & 15, g = lane >> 4;
    int gw4 = (r & 3) << 4;
    int v = blockIdx.x * 16 + r;

    // B fragments first (global-load latency overlaps the gather)
    f16x8 B0, B1;
    {
        int n = (w << 4) + m;
        const float* wp = W + (g << 3) * 64 + n;
#pragma unroll
        for (int j = 0; j < 8; ++j) B0[j] = (_Float16)wp[j * 64];
        wp += 32 * 64;
#pragma unroll
        for (int j = 0; j < 8; ++j) B1[j] = (_Float16)wp[j * 64];
    }
    if (blockIdx.x == 0 && tid < 16)
        hs_out[(size_t)N * 16 + tid] = 0u;               // zero pad row for gather2

    float dv = 0.f;
    float4 h = make_float4(0.f, 0.f, 0.f, 0.f);
    if (v < N) {
        dv = dinv[v];
        float4 bv = ((const float4*)bias)[l];
        float4 acc = gather_rows(hs8, csr, off[v], off[v + 1], v, l, gw4, N);
        h.x = fmaxf(acc.x * dv + bv.x, 0.f);
        h.y = fmaxf(acc.y * dv + bv.y, 0.f);
        h.z = fmaxf(acc.z * dv + bv.z, 0.f);
        h.w = fmaxf(acc.w * dv + bv.w, 0.f);
    }
    {
        f16x4 hv;
        hv[0] = (_Float16)h.x; hv[1] = (_Float16)h.y;
        hv[2] = (_Float16)h.z; hv[3] = (_Float16)h.w;
        *(f16x4*)(Xs + r * 72 + (l << 2)) = hv;
    }
    __syncthreads();

    f16x8 A0 = *(const f16x8*)(Xs + m * 72 + (g << 3));
    f16x8 A1 = *(const f16x8*)(Xs + m * 72 + 32 + (g << 3));
    f32x4 acc2 = {0.f, 0.f, 0.f, 0.f};
    acc2 = __builtin_amdgcn_mfma_f32_16x16x32_f16(A0, B0, acc2, 0, 0, 0);
    acc2 = __builtin_amdgcn_mfma_f32_16x16x32_f16(A1, B1, acc2, 0, 0, 0);
#pragma unroll
    for (int j = 0; j < 4; ++j)
        Os[((g << 2) + j) * 68 + (w << 4) + m] = acc2[j];
    __syncthreads();

    if (v < N) {
        float4 o = *(const float4*)(Os + r * 68 + (l << 2));
        int p = 0;
        p = __builtin_amdgcn_cvt_pk_fp8_f32(o.x * dv, o.y * dv, p, false);
        p = __builtin_amdgcn_cvt_pk_fp8_f32(o.z * dv, o.w * dv, p, true);
        hs_out[(size_t)v * 16 + l] = (unsigned int)p;
    }
}

// ---------------- fused gather (layer 2) + mean-pool: atomics into out ----------------
// block = 16 nodes; batch sorted -> 1-2 graph segments per block. Each group computes
// relu(acc*dinv+b2)/count[g]; segment leaders reduce over LDS and atomicAdd into out.

__global__ __launch_bounds__(256) void k_gather_pool(const unsigned int* __restrict__ hs8,
                                                     const int* __restrict__ csr,
                                                     const int* __restrict__ off,
                                                     const float* __restrict__ dinv,
                                                     const float* __restrict__ bias,
                                                     const int* __restrict__ batch,
                                                     const int* __restrict__ goff,
                                                     float* __restrict__ out, int N) {
    __shared__ float vals[16][68];
    __shared__ int gid[16];
    int tid = threadIdx.x;
    int r = tid >> 4, l = tid & 15;
    int gw4 = (r & 3) << 4;
    int v = blockIdx.x * 16 + r;

    float4 val = make_float4(0.f, 0.f, 0.f, 0.f);
    int g = -1;
    if (v < N) {
        g = batch[v];
        float dv = dinv[v];
        float4 bv = ((const float4*)bias)[l];
        float4 acc = gather_rows(hs8, csr, off[v], off[v + 1], v, l, gw4, N);
        float inv = 1.0f / (float)(goff[g + 1] - goff[g]);
        val.x = fmaxf(acc.x * dv + bv.x, 0.f) * inv;
        val.y = fmaxf(acc.y * dv + bv.y, 0.f) * inv;
        val.z = fmaxf(acc.z * dv + bv.z, 0.f) * inv;
        val.w = fmaxf(acc.w * dv + bv.w, 0.f) * inv;
    }
    *(float4*)(&vals[r][l << 2]) = val;
    if (l == 0) gid[r] = g;
    __syncthreads();

    if (v < N) {
        bool leader = (r == 0) || (gid[r - 1] != g);
        if (leader) {
            float4 sacc = val;
            for (int rr = r + 1; rr < 16 && gid[rr] == g; ++rr) {
                float4 t = *(const float4*)(&vals[rr][l << 2]);
                sacc.x += t.x; sacc.y += t.y; sacc.z += t.z; sacc.w += t.w;
            }
            float* op = out + (size_t)g * DIM + (l << 2);
            atomicAdd(op + 0, sacc.x);
            atomicAdd(op + 1, sacc.y);
            atomicAdd(op + 2, sacc.z);
            atomicAdd(op + 3, sacc.w);
        }
    }
}

// ---------------- launch ----------------

static inline int cdiv(int a, int b) { return (a + b - 1) / b; }

extern "C" void kernel_launch(void* const* d_in, const int* in_sizes, int n_in,
                              void* d_out, int out_size, void* d_ws, size_t ws_size,
                              hipStream_t stream) {
    const float* x   = (const float*)d_in[0];
    const float* W1  = (const float*)d_in[1];
    const float* b1  = (const float*)d_in[2];
    const float* W2  = (const float*)d_in[3];
    const float* b2  = (const float*)d_in[4];
    const int*   ei  = (const int*)d_in[5];
    const int*   bat = (const int*)d_in[6];

    const int N = in_sizes[0] / DIM;
    const int E = in_sizes[5] / 2;
    const int G = out_size / DIM;
    const int* src = ei;
    const int* dst = ei + E;
    float* out = (float*)d_out;

    // workspace: hs1 | hs2 | dinv | off | cur | goff | deg | bsums | csr
    __half* hs1    = (__half*)d_ws;                         // (N+1)*64 h region (fp8 uses half)
    __half* hs2    = hs1 + (size_t)(N + 1) * DIM;           // (N+1)*64 h region
    float*  dinv   = (float*)(hs2 + (size_t)(N + 1) * DIM); // N f
    int*    off    = (int*)(dinv + N);                      // N+1 i
    int*    cur    = off + (N + 1);                         // N i
    int*    goff   = cur + N;                               // G+1 i
    int*    deg    = goff + (G + 1);                        // N i
    int*    bsums  = deg + N;                               // up to 64 i
    int*    csr    = bsums + 64;                            // E i

    k_zero<<<512, 256, 0, stream>>>(deg, out, N, G * DIM);
    k_deg<<<2048, 256, 0, stream>>>(dst, deg, E);
    int nblk = cdiv(N, 4096);
    k_scanA2<<<nblk, 1024, 0, stream>>>(deg, off, bsums, N);
    k_scanC<<<nblk, 1024, 0, stream>>>(off, cur, bsums, deg, bat, dinv, goff, N, G, E);
    k_scatter<<<2048, 256, 0, stream>>>(src, dst, cur, csr, E);

    // layer 1 transform: hs1 = (x @ W1) * dinv (fp8 e4m3), MFMA
    k_gemm<<<cdiv(N + 1, 16), 256, 0, stream>>>(x, W1, dinv, (unsigned int*)hs1, N);

    // fused: agg1 = gather(hs1)+b1 ; hs2 = (relu(agg1) @ W2) * dinv (fp8), MFMA
    k_gather_gemm<<<cdiv(N, 16), 256, 0, stream>>>((const unsigned int*)hs1, csr, off,
                                                   dinv, b1, W2, (unsigned int*)hs2, N);

    // fused: layer 2 gather + bias + relu + mean-pool (atomics into out)
    k_gather_pool<<<cdiv(N, 16), 256, 0, stream>>>((const unsigned int*)hs2, csr, off,
                                                   dinv, b2, bat, goff, out, N);
}

// Round 10
// 219.381 us; speedup vs baseline: 1.5923x; 1.5923x over previous
//
#include <hip/hip_runtime.h>
#include <hip/hip_fp16.h>

#define DIM 64
#define BIN_SHIFT 7
#define BINSZ 128      // nodes per bin
#define MAXBINS 1024   // supports N up to 131072
#define PB 512         // edge-slice blocks (block-major bkt regions)

typedef __attribute__((ext_vector_type(2))) float floatx2;
typedef __attribute__((ext_vector_type(4))) float f32x4;
typedef __attribute__((ext_vector_type(8))) _Float16 f16x8;
typedef __attribute__((ext_vector_type(4))) _Float16 f16x4;

// ---------------- pass 0: zero bintot + pooled output ----------------

__global__ __launch_bounds__(256) void k_zero(int* __restrict__ bintot,
                                              float* __restrict__ out,
                                              int NBZ, int GD) {
    int i = blockIdx.x * 256 + threadIdx.x;
    int stride = gridDim.x * 256;
    for (int j = i; j < NBZ; j += stride) bintot[j] = 0;
    for (int j = i; j < GD; j += stride) out[j] = 0.f;
}

// ---------------- pass 1: block-major bucket sort of each edge slice ----------------
// Each block: LDS hist of its 3125-edge slice -> in-block 782-bin shfl scan -> scatter
// into its OWN contiguous bkt region (coalesced, no cross-block false sharing).
// Publishes per-bin offsets C[blk*NB+i] / lengths LEN[blk*NB+i] (coalesced) and
// atomically accumulates bintot.

__global__ __launch_bounds__(256) void k_bucket3(const int* __restrict__ src,
                                                 const int* __restrict__ dst,
                                                 int* __restrict__ bintot,
                                                 int* __restrict__ C,
                                                 int* __restrict__ LEN,
                                                 int* __restrict__ bkt, int E, int NB) {
    __shared__ int cnt[MAXBINS], bas[MAXBINS];
    __shared__ int ws[4];
    int tid = threadIdx.x, blk = blockIdx.x;
    for (int i = tid; i < NB; i += 256) cnt[i] = 0;
    __syncthreads();
    int per = (E + PB - 1) / PB;
    int e0 = blk * per;
    int e1 = e0 + per; if (e1 > E) e1 = E;
    for (int e = e0 + tid; e < e1; e += 256)
        atomicAdd(&cnt[dst[e] >> BIN_SHIFT], 1);
    __syncthreads();
    // in-block exclusive scan of cnt[0..NB) -> bas (thread t owns bins 4t..4t+3)
    int j0 = tid * 4;
    int v[4]; int sum = 0;
#pragma unroll
    for (int t = 0; t < 4; ++t) {
        int j = j0 + t;
        int x = (j < NB) ? cnt[j] : 0;
        v[t] = sum; sum += x;
    }
    int lane = tid & 63, wv = tid >> 6;
    int x = sum;
#pragma unroll
    for (int d = 1; d < 64; d <<= 1) {
        int t = __shfl_up(x, d);
        if (lane >= d) x += t;
    }
    if (lane == 63) ws[wv] = x;
    __syncthreads();
    int prefix = 0;
    for (int w = 0; w < wv; ++w) prefix += ws[w];
    int ex = prefix + x - sum;
#pragma unroll
    for (int t = 0; t < 4; ++t) {
        int j = j0 + t;
        if (j < NB) bas[j] = ex + v[t];
    }
    __syncthreads();
    int nbb = blk * NB;
    for (int i = tid; i < NB; i += 256) {
        int c = cnt[i];
        C[nbb + i] = bas[i];
        LEN[nbb + i] = c;
        if (c) atomicAdd(&bintot[i], c);
        cnt[i] = 0;                      // reuse as scatter cursor
    }
    __syncthreads();
    for (int e = e0 + tid; e < e1; e += 256) {
        int d = dst[e];
        int bb = d >> BIN_SHIFT;
        int pos = bas[bb] + atomicAdd(&cnt[bb], 1);
        bkt[e0 + pos] = src[e] | ((d & (BINSZ - 1)) << 24);
    }
}

// ---------------- pass 2: single-block shfl scan of bin totals -> binoff ----------------

__global__ __launch_bounds__(256) void k_scan782(const int* __restrict__ bintot,
                                                 int* __restrict__ binoff, int NB, int E) {
    __shared__ int ws[4];
    int tid = threadIdx.x;
    int j0 = tid * 4;
    int v[4]; int sum = 0;
#pragma unroll
    for (int t = 0; t < 4; ++t) {
        int j = j0 + t;
        int x = (j < NB) ? bintot[j] : 0;
        v[t] = sum; sum += x;
    }
    int lane = tid & 63, wv = tid >> 6;
    int x = sum;
#pragma unroll
    for (int d = 1; d < 64; d <<= 1) {
        int t = __shfl_up(x, d);
        if (lane >= d) x += t;
    }
    if (lane == 63) ws[wv] = x;
    __syncthreads();
    int prefix = 0;
    for (int w = 0; w < wv; ++w) prefix += ws[w];
    int ex = prefix + x - sum;
#pragma unroll
    for (int t = 0; t < 4; ++t) {
        int j = j0 + t;
        if (j < NB) binoff[j] = ex + v[t];
    }
    if (tid == 255) binoff[NB] = prefix + x;   // == E
}

// ---------------- pass 3: per-bin counting sort from 512 fragments -> csr, off, dinv; + gbound ----------------
// Bin b's edges live in fragments bkt[f*per + C[f*NB+b] .. +LEN[f*NB+b]); thread t owns
// fragments 2t, 2t+1. csr writes stay contiguous per bin (as before).

__global__ __launch_bounds__(256) void k_binsort2(const int* __restrict__ bkt,
                                                  const int* __restrict__ C,
                                                  const int* __restrict__ LEN,
                                                  const int* __restrict__ binoff,
                                                  int* __restrict__ csr,
                                                  int* __restrict__ off,
                                                  float* __restrict__ dinv,
                                                  const int* __restrict__ batch,
                                                  int* __restrict__ goff,
                                                  int N, int G, int E, int NB) {
    __shared__ int cnt[BINSZ], bas[BINSZ], cur[BINSZ];
    __shared__ int wsum[4];
    int tid = threadIdx.x;
    int b = blockIdx.x;
    int per = (E + PB - 1) / PB;
    int s0 = binoff[b];
    if (tid < BINSZ) { cnt[tid] = 0; cur[tid] = 0; }
    __syncthreads();
    int f0 = tid * 2;
    int ca = C[f0 * NB + b],       lna = LEN[f0 * NB + b];
    int cb = C[(f0 + 1) * NB + b], lnb = LEN[(f0 + 1) * NB + b];
    const int* pa  = bkt + f0 * per + ca;
    const int* pb_ = bkt + (f0 + 1) * per + cb;
    for (int j = 0; j < lna; ++j) atomicAdd(&cnt[(pa[j]  >> 24) & (BINSZ - 1)], 1);
    for (int j = 0; j < lnb; ++j) atomicAdd(&cnt[(pb_[j] >> 24) & (BINSZ - 1)], 1);
    __syncthreads();
    int my = (tid < BINSZ) ? cnt[tid] : 0;
    int lane = tid & 63, wv = tid >> 6;
    int x = my;
#pragma unroll
    for (int d = 1; d < 64; d <<= 1) {
        int t = __shfl_up(x, d);
        if (lane >= d) x += t;
    }
    if (lane == 63) wsum[wv] = x;
    __syncthreads();
    int prefix = 0;
    for (int w = 0; w < wv; ++w) prefix += wsum[w];
    int ex = x + prefix - my;               // exclusive base
    if (tid < BINSZ) {
        bas[tid] = ex;
        int v = (b << BIN_SHIFT) + tid;
        if (v < N) {
            off[v] = s0 + ex;
            dinv[v] = rsqrtf((float)(my + 1));   // +1 self-loop
            if (v == N - 1) off[N] = E;
            // fused gbound (batch sorted)
            int bb = batch[v];
            int prev = (v == 0) ? -1 : batch[v - 1];
            for (int g = prev + 1; g <= bb; ++g) goff[g] = v;
            if (v == N - 1)
                for (int g = bb + 1; g <= G; ++g) goff[g] = N;
        }
    }
    __syncthreads();
    for (int j = 0; j < lna; ++j) {
        int p = pa[j];
        int lo = (p >> 24) & (BINSZ - 1);
        int li = atomicAdd(&cur[lo], 1);
        csr[s0 + bas[lo] + li] = p & 0xFFFFFF;
    }
    for (int j = 0; j < lnb; ++j) {
        int p = pb_[j];
        int lo = (p >> 24) & (BINSZ - 1);
        int li = atomicAdd(&cur[lo], 1);
        csr[s0 + bas[lo] + li] = p & 0xFFFFFF;
    }
}

// ---------------- skinny GEMM via MFMA: hs[row] = (X[row] @ W) * dinv[row], fp8 out ----------------
// Wave w computes the 16-row x 16-col tile at cols [16w,16w+16).
// k-map bijection: k = 32s + 8*(lane>>4) + elem, applied to BOTH A and B fragments.
// D layout (HW-verified): col = lane&15, row = 4*(lane>>4) + reg.

__global__ __launch_bounds__(256) void k_gemm(const float* __restrict__ X,
                                              const float* __restrict__ W,
                                              const float* __restrict__ dinv,
                                              unsigned int* __restrict__ Y8, int N) {
    __shared__ float Os[16 * 68];
    int tid = threadIdx.x;
    int lane = tid & 63, w = tid >> 6;
    int m = lane & 15, g = lane >> 4;
    int row0 = blockIdx.x * 16;
    int row = row0 + m;

    // B fragments from global W (row-major [k][n]); L1-hot
    f16x8 B0, B1;
    {
        int n = (w << 4) + m;
        const float* wp = W + (g << 3) * 64 + n;
#pragma unroll
        for (int j = 0; j < 8; ++j) B0[j] = (_Float16)wp[j * 64];
        wp += 32 * 64;
#pragma unroll
        for (int j = 0; j < 8; ++j) B1[j] = (_Float16)wp[j * 64];
    }
    // A fragments straight from global X
    f16x8 A0, A1;
    {
        float4 u0 = make_float4(0.f, 0.f, 0.f, 0.f), u1 = u0, u2 = u0, u3 = u0;
        if (row < N) {
            const float* xp = X + (size_t)row * DIM + (g << 3);
            u0 = *(const float4*)(xp);
            u1 = *(const float4*)(xp + 4);
            u2 = *(const float4*)(xp + 32);
            u3 = *(const float4*)(xp + 36);
        }
        A0[0] = (_Float16)u0.x; A0[1] = (_Float16)u0.y; A0[2] = (_Float16)u0.z; A0[3] = (_Float16)u0.w;
        A0[4] = (_Float16)u1.x; A0[5] = (_Float16)u1.y; A0[6] = (_Float16)u1.z; A0[7] = (_Float16)u1.w;
        A1[0] = (_Float16)u2.x; A1[1] = (_Float16)u2.y; A1[2] = (_Float16)u2.z; A1[3] = (_Float16)u2.w;
        A1[4] = (_Float16)u3.x; A1[5] = (_Float16)u3.y; A1[6] = (_Float16)u3.z; A1[7] = (_Float16)u3.w;
    }
    f32x4 acc = {0.f, 0.f, 0.f, 0.f};
    acc = __builtin_amdgcn_mfma_f32_16x16x32_f16(A0, B0, acc, 0, 0, 0);
    acc = __builtin_amdgcn_mfma_f32_16x16x32_f16(A1, B1, acc, 0, 0, 0);
#pragma unroll
    for (int j = 0; j < 4; ++j)
        Os[((g << 2) + j) * 68 + (w << 4) + m] = acc[j];
    __syncthreads();

    int r = tid >> 4, c = tid & 15;
    int orow = row0 + r;
    if (orow < N) {
        float4 o = *(const float4*)(Os + r * 68 + (c << 2));
        float s = dinv[orow];
        int p = 0;
        p = __builtin_amdgcn_cvt_pk_fp8_f32(o.x * s, o.y * s, p, false);
        p = __builtin_amdgcn_cvt_pk_fp8_f32(o.z * s, o.w * s, p, true);
        Y8[(size_t)orow * 16 + c] = (unsigned int)p;
    } else if (orow == N) {
        Y8[(size_t)orow * 16 + c] = 0u;   // +0 in e4m3 (gather pad row)
    }
}

// ---------------- gather core: 16-lane group per node, 16 edges / 16 loads in flight ----------------
// lane l owns cols 4l..4l+3 (one uint of the fp8 row). Padding slots read row N (zeros,
// single broadcast cacheline). All 16 loads issued before any conversion.

__device__ __forceinline__ float4 gather_rows(const unsigned int* __restrict__ hs8,
                                              const int* __restrict__ csr,
                                              int k0, int k1, int v, int l, int gw4,
                                              int N) {
    float4 a0, a1, a2, a3;
    {
        unsigned int u = hs8[(unsigned)((v << 4) | l)];    // self-loop term
        floatx2 f0 = __builtin_amdgcn_cvt_pk_f32_fp8((int)u, false);
        floatx2 f1 = __builtin_amdgcn_cvt_pk_f32_fp8((int)u, true);
        a0 = make_float4(f0.x, f0.y, f1.x, f1.y);
        a1 = make_float4(0.f, 0.f, 0.f, 0.f);
        a2 = make_float4(0.f, 0.f, 0.f, 0.f);
        a3 = make_float4(0.f, 0.f, 0.f, 0.f);
    }
    for (int kb = k0; kb < k1; kb += 16) {
        int rem = k1 - kb;
        int idx = (l < rem) ? csr[kb + l] : N;
        unsigned uu[16];
#pragma unroll
        for (int t = 0; t < 16; ++t) {
            int s = __shfl(idx, gw4 + t);
            uu[t] = hs8[(unsigned)((s << 4) | l)];
        }
#pragma unroll
        for (int t = 0; t < 16; t += 4) {
            floatx2 q0 = __builtin_amdgcn_cvt_pk_f32_fp8((int)uu[t + 0], false);
            floatx2 q1 = __builtin_amdgcn_cvt_pk_f32_fp8((int)uu[t + 0], true);
            floatx2 q2 = __builtin_amdgcn_cvt_pk_f32_fp8((int)uu[t + 1], false);
            floatx2 q3 = __builtin_amdgcn_cvt_pk_f32_fp8((int)uu[t + 1], true);
            floatx2 q4 = __builtin_amdgcn_cvt_pk_f32_fp8((int)uu[t + 2], false);
            floatx2 q5 = __builtin_amdgcn_cvt_pk_f32_fp8((int)uu[t + 2], true);
            floatx2 q6 = __builtin_amdgcn_cvt_pk_f32_fp8((int)uu[t + 3], false);
            floatx2 q7 = __builtin_amdgcn_cvt_pk_f32_fp8((int)uu[t + 3], true);
            a0.x += q0.x; a0.y += q0.y; a0.z += q1.x; a0.w += q1.y;
            a1.x += q2.x; a1.y += q2.y; a1.z += q3.x; a1.w += q3.y;
            a2.x += q4.x; a2.y += q4.y; a2.z += q5.x; a2.w += q5.y;
            a3.x += q6.x; a3.y += q6.y; a3.z += q7.x; a3.w += q7.y;
        }
    }
    return make_float4(a0.x + a1.x + a2.x + a3.x,
                       a0.y + a1.y + a2.y + a3.y,
                       a0.z + a1.z + a2.z + a3.z,
                       a0.w + a1.w + a2.w + a3.w);
}

// ---------------- fused gather + MFMA GEMM (layer 1 -> hs2 fp8 directly) ----------------
// block = 256 threads = 16 nodes. gathered row relu'd into fp16 LDS tile, MFMA vs W2
// fragments (built from global, no W LDS), fp32 epilogue transpose via Os, fp8 out.

__global__ __launch_bounds__(256) void k_gather_gemm(const unsigned int* __restrict__ hs8,
                                                     const int* __restrict__ csr,
                                                     const int* __restrict__ off,
                                                     const float* __restrict__ dinv,
                                                     const float* __restrict__ bias,
                                                     const float* __restrict__ W,
                                                     unsigned int* __restrict__ hs_out,
                                                     int N) {
    __shared__ _Float16 Xs[16 * 72];
    __shared__ float Os[16 * 68];
    int tid = threadIdx.x;
    int r = tid >> 4, l = tid & 15;
    int lane = tid & 63, w = tid >> 6;
    int m = lane & 15, g = lane >> 4;
    int gw4 = (r & 3) << 4;
    int v = blockIdx.x * 16 + r;

    // B fragments first (global-load latency overlaps the gather)
    f16x8 B0, B1;
    {
        int n = (w << 4) + m;
        const float* wp = W + (g << 3) * 64 + n;
#pragma unroll
        for (int j = 0; j < 8; ++j) B0[j] = (_Float16)wp[j * 64];
        wp += 32 * 64;
#pragma unroll
        for (int j = 0; j < 8; ++j) B1[j] = (_Float16)wp[j * 64];
    }
    if (blockIdx.x == 0 && tid < 16)
        hs_out[(size_t)N * 16 + tid] = 0u;               // zero pad row for gather2

    float dv = 0.f;
    float4 h = make_float4(0.f, 0.f, 0.f, 0.f);
    if (v < N) {
        dv = dinv[v];
        float4 bv = ((const float4*)bias)[l];
        float4 acc = gather_rows(hs8, csr, off[v], off[v + 1], v, l, gw4, N);
        h.x = fmaxf(acc.x * dv + bv.x, 0.f);
        h.y = fmaxf(acc.y * dv + bv.y, 0.f);
        h.z = fmaxf(acc.z * dv + bv.z, 0.f);
        h.w = fmaxf(acc.w * dv + bv.w, 0.f);
    }
    {
        f16x4 hv;
        hv[0] = (_Float16)h.x; hv[1] = (_Float16)h.y;
        hv[2] = (_Float16)h.z; hv[3] = (_Float16)h.w;
        *(f16x4*)(Xs + r * 72 + (l << 2)) = hv;
    }
    __syncthreads();

    f16x8 A0 = *(const f16x8*)(Xs + m * 72 + (g << 3));
    f16x8 A1 = *(const f16x8*)(Xs + m * 72 + 32 + (g << 3));
    f32x4 acc2 = {0.f, 0.f, 0.f, 0.f};
    acc2 = __builtin_amdgcn_mfma_f32_16x16x32_f16(A0, B0, acc2, 0, 0, 0);
    acc2 = __builtin_amdgcn_mfma_f32_16x16x32_f16(A1, B1, acc2, 0, 0, 0);
#pragma unroll
    for (int j = 0; j < 4; ++j)
        Os[((g << 2) + j) * 68 + (w << 4) + m] = acc2[j];
    __syncthreads();

    if (v < N) {
        float4 o = *(const float4*)(Os + r * 68 + (l << 2));
        int p = 0;
        p = __builtin_amdgcn_cvt_pk_fp8_f32(o.x * dv, o.y * dv, p, false);
        p = __builtin_amdgcn_cvt_pk_fp8_f32(o.z * dv, o.w * dv, p, true);
        hs_out[(size_t)v * 16 + l] = (unsigned int)p;
    }
}

// ---------------- fused gather (layer 2) + mean-pool: atomics into out ----------------
// block = 16 nodes; batch sorted -> 1-2 graph segments per block. Each group computes
// relu(acc*dinv+b2)/count[g]; segment leaders reduce over LDS and atomicAdd into out.

__global__ __launch_bounds__(256) void k_gather_pool(const unsigned int* __restrict__ hs8,
                                                     const int* __restrict__ csr,
                                                     const int* __restrict__ off,
                                                     const float* __restrict__ dinv,
                                                     const float* __restrict__ bias,
                                                     const int* __restrict__ batch,
                                                     const int* __restrict__ goff,
                                                     float* __restrict__ out, int N) {
    __shared__ float vals[16][68];
    __shared__ int gid[16];
    int tid = threadIdx.x;
    int r = tid >> 4, l = tid & 15;
    int gw4 = (r & 3) << 4;
    int v = blockIdx.x * 16 + r;

    float4 val = make_float4(0.f, 0.f, 0.f, 0.f);
    int g = -1;
    if (v < N) {
        g = batch[v];
        float dv = dinv[v];
        float4 bv = ((const float4*)bias)[l];
        float4 acc = gather_rows(hs8, csr, off[v], off[v + 1], v, l, gw4, N);
        float inv = 1.0f / (float)(goff[g + 1] - goff[g]);
        val.x = fmaxf(acc.x * dv + bv.x, 0.f) * inv;
        val.y = fmaxf(acc.y * dv + bv.y, 0.f) * inv;
        val.z = fmaxf(acc.z * dv + bv.z, 0.f) * inv;
        val.w = fmaxf(acc.w * dv + bv.w, 0.f) * inv;
    }
    *(float4*)(&vals[r][l << 2]) = val;
    if (l == 0) gid[r] = g;
    __syncthreads();

    if (v < N) {
        bool leader = (r == 0) || (gid[r - 1] != g);
        if (leader) {
            float4 sacc = val;
            for (int rr = r + 1; rr < 16 && gid[rr] == g; ++rr) {
                float4 t = *(const float4*)(&vals[rr][l << 2]);
                sacc.x += t.x; sacc.y += t.y; sacc.z += t.z; sacc.w += t.w;
            }
            float* op = out + (size_t)g * DIM + (l << 2);
            atomicAdd(op + 0, sacc.x);
            atomicAdd(op + 1, sacc.y);
            atomicAdd(op + 2, sacc.z);
            atomicAdd(op + 3, sacc.w);
        }
    }
}

// ---------------- launch ----------------

static inline int cdiv(int a, int b) { return (a + b - 1) / b; }

extern "C" void kernel_launch(void* const* d_in, const int* in_sizes, int n_in,
                              void* d_out, int out_size, void* d_ws, size_t ws_size,
                              hipStream_t stream) {
    const float* x   = (const float*)d_in[0];
    const float* W1  = (const float*)d_in[1];
    const float* b1  = (const float*)d_in[2];
    const float* W2  = (const float*)d_in[3];
    const float* b2  = (const float*)d_in[4];
    const int*   ei  = (const int*)d_in[5];
    const int*   bat = (const int*)d_in[6];

    const int N = in_sizes[0] / DIM;
    const int E = in_sizes[5] / 2;
    const int G = out_size / DIM;
    const int NB = cdiv(N, BINSZ);           // <= MAXBINS
    const int* src = ei;
    const int* dst = ei + E;
    float* out = (float*)d_out;

    // workspace: hs1 | hs2 | dinv | off | goff | bintot | binoff | C | LEN | csr
    // bkt aliases hs1 (dead before gemm1 writes hs1).
    __half* hs1    = (__half*)d_ws;                         // (N+1)*64 h region (fp8 uses half)
    __half* hs2    = hs1 + (size_t)(N + 1) * DIM;           // (N+1)*64 h region
    float*  dinv   = (float*)(hs2 + (size_t)(N + 1) * DIM); // N f
    int*    off    = (int*)(dinv + N);                      // N+1 i
    int*    goff   = off + (N + 1);                         // G+1 i
    int*    bintot = goff + (G + 1);                        // MAXBINS i
    int*    binoff = bintot + MAXBINS;                      // MAXBINS+1 i
    int*    C      = binoff + (MAXBINS + 1);                // PB*NB i (block-major)
    int*    LEN    = C + (size_t)PB * NB;                   // PB*NB i (block-major)
    int*    csr    = LEN + (size_t)PB * NB;                 // E i
    int*    bkt    = (int*)hs1;                             // PB*per i (aliased)

    k_zero<<<256, 256, 0, stream>>>(bintot, out, MAXBINS, G * DIM);
    k_bucket3<<<PB, 256, 0, stream>>>(src, dst, bintot, C, LEN, bkt, E, NB);
    k_scan782<<<1, 256, 0, stream>>>(bintot, binoff, NB, E);
    k_binsort2<<<NB, 256, 0, stream>>>(bkt, C, LEN, binoff, csr, off, dinv, bat,
                                       goff, N, G, E, NB);

    // layer 1 transform: hs1 = (x @ W1) * dinv (fp8 e4m3), MFMA
    k_gemm<<<cdiv(N + 1, 16), 256, 0, stream>>>(x, W1, dinv, (unsigned int*)hs1, N);

    // fused: agg1 = gather(hs1)+b1 ; hs2 = (relu(agg1) @ W2) * dinv (fp8), MFMA
    k_gather_gemm<<<cdiv(N, 16), 256, 0, stream>>>((const unsigned int*)hs1, csr, off,
                                                   dinv, b1, W2, (unsigned int*)hs2, N);

    // fused: layer 2 gather + bias + relu + mean-pool (atomics into out)
    k_gather_pool<<<cdiv(N, 16), 256, 0, stream>>>((const unsigned int*)hs2, csr, off,
                                                   dinv, b2, bat, goff, out, N);
}

// Round 11
// 192.141 us; speedup vs baseline: 1.8181x; 1.1418x over previous
//
#include <hip/hip_runtime.h>
#include <hip/hip_fp16.h>

#define DIM 64
#define BIN_SHIFT 7
#define BINSZ 128      // nodes per bin
#define MAXBINS 1024   // supports N up to 131072
#define PB 512         // edge-slice blocks for hist/bucket (power of 2)
#define PB_LOG 9

typedef __attribute__((ext_vector_type(2))) float floatx2;
typedef __attribute__((ext_vector_type(4))) float f32x4;
typedef __attribute__((ext_vector_type(8))) _Float16 f16x8;
typedef __attribute__((ext_vector_type(4))) _Float16 f16x4;

// ---------------- pass 1: per-block LDS histogram -> C[blk][bin] ----------------

__global__ __launch_bounds__(256) void k_hist(const int* __restrict__ dst,
                                              int* __restrict__ C, int E, int NB) {
    __shared__ int h[MAXBINS];
    for (int i = threadIdx.x; i < NB; i += 256) h[i] = 0;
    __syncthreads();
    int per = (E + PB - 1) / PB;
    int e0 = blockIdx.x * per;
    int e1 = e0 + per; if (e1 > E) e1 = E;
    for (int e = e0 + (int)threadIdx.x; e < e1; e += 256)
        atomicAdd(&h[dst[e] >> BIN_SHIFT], 1);
    __syncthreads();
    for (int i = threadIdx.x; i < NB; i += 256)
        C[blockIdx.x * NB + i] = h[i];
}

// ---------------- pass 2a: chunk-local exclusive scan of C (bin-major order) ----------------

__global__ __launch_bounds__(1024) void k_scanA(const int* __restrict__ C,
                                                int* __restrict__ S,
                                                int* __restrict__ bsums, int NB, int M) {
    __shared__ int sh[1024];
    int tid = threadIdx.x;
    int j0 = blockIdx.x * 4096 + tid * 4;
    int v[4]; int sum = 0;
#pragma unroll
    for (int t = 0; t < 4; ++t) {
        int j = j0 + t; int x = 0;
        if (j < M) { int bin = j >> PB_LOG, blk = j & (PB - 1); x = C[blk * NB + bin]; }
        v[t] = sum; sum += x;
    }
    sh[tid] = sum;
    __syncthreads();
#pragma unroll
    for (int d = 1; d < 1024; d <<= 1) {
        int t = (tid >= d) ? sh[tid - d] : 0;
        __syncthreads();
        sh[tid] += t;
        __syncthreads();
    }
    int excl = sh[tid] - sum;
#pragma unroll
    for (int t = 0; t < 4; ++t) {
        int j = j0 + t;
        if (j < M) S[j] = excl + v[t];
    }
    if (tid == 1023) bsums[blockIdx.x] = sh[1023];
}

// ---------------- pass 2b: exclusive scan of chunk sums ----------------

__global__ __launch_bounds__(1024) void k_scanB(int* __restrict__ bsums, int nb) {
    __shared__ int s[1024];
    int tid = threadIdx.x;
    int v = (tid < nb) ? bsums[tid] : 0;
    s[tid] = v;
    __syncthreads();
#pragma unroll
    for (int d = 1; d < 1024; d <<= 1) {
        int t = (tid >= d) ? s[tid - d] : 0;
        __syncthreads();
        s[tid] += t;
        __syncthreads();
    }
    if (tid < nb) bsums[tid] = s[tid] - v;
}

// ---------------- pass 3: one-pass bucket scatter, LDS cursors ----------------
// XCD-clustered slice mapping: bkt is bin-major, so fragments of consecutive blk are
// adjacent 64B regions. HW round-robins blocks over the 8 XCDs; remapping
// blk = (bid&7)*64 + (bid>>3) (bijective for PB=512) gives each XCD a contiguous
// 64-slice range -> each bin's fragment neighborhood is written by ONE XCD's L2
// (kills the cross-XCD false sharing / partial-line writebacks seen in R7: 36MB WB).

__global__ __launch_bounds__(256) void k_bucket(const int* __restrict__ src,
                                                const int* __restrict__ dst,
                                                const int* __restrict__ S,
                                                const int* __restrict__ bsums,
                                                int* __restrict__ bkt, int E, int NB) {
    __shared__ int lcur[MAXBINS];
    int blk = ((blockIdx.x & 7) << 6) | (blockIdx.x >> 3);   // XCD-clustered slice id
    for (int i = threadIdx.x; i < NB; i += 256) {
        int j = i * PB + blk;
        lcur[i] = S[j] + bsums[j >> 12];
    }
    __syncthreads();
    int per = (E + PB - 1) / PB;
    int e0 = blk * per;
    int e1 = e0 + per; if (e1 > E) e1 = E;
    for (int e = e0 + (int)threadIdx.x; e < e1; e += 256) {
        int d = dst[e];
        int pos = atomicAdd(&lcur[d >> BIN_SHIFT], 1);
        bkt[pos] = src[e] | ((d & (BINSZ - 1)) << 24);
    }
}

// ---------------- pass 4: per-bin counting sort -> csr, off, dinv; + gbound; + zero out ----------------

__global__ __launch_bounds__(256) void k_binsort(const int* __restrict__ bkt,
                                                 const int* __restrict__ S,
                                                 const int* __restrict__ bsums,
                                                 int* __restrict__ csr,
                                                 int* __restrict__ off,
                                                 float* __restrict__ dinv,
                                                 const int* __restrict__ batch,
                                                 int* __restrict__ goff,
                                                 float* __restrict__ outz,
                                                 int N, int G, int E, int NB) {
    __shared__ int cnt[BINSZ], bas[BINSZ], cur[BINSZ];
    __shared__ int wsum[4];
    int tid = threadIdx.x;
    int b = blockIdx.x;
    // zero the pooled output (k_gather_pool accumulates via atomics)
    for (int i = b * 256 + tid; i < G * DIM; i += NB * 256) outz[i] = 0.f;
    int j0 = b << PB_LOG;
    int s0 = S[j0] + bsums[j0 >> 12];
    int s1 = E;
    if (b + 1 < NB) { int j1 = (b + 1) << PB_LOG; s1 = S[j1] + bsums[j1 >> 12]; }
    if (tid < BINSZ) { cnt[tid] = 0; cur[tid] = 0; }
    __syncthreads();
    for (int i = s0 + tid; i < s1; i += 256)
        atomicAdd(&cnt[(bkt[i] >> 24) & (BINSZ - 1)], 1);
    __syncthreads();
    int my = (tid < BINSZ) ? cnt[tid] : 0;
    int lane = tid & 63, wv = tid >> 6;
    int x = my;
#pragma unroll
    for (int d = 1; d < 64; d <<= 1) {
        int t = __shfl_up(x, d);
        if (lane >= d) x += t;
    }
    if (lane == 63) wsum[wv] = x;
    __syncthreads();
    int prefix = 0;
    for (int w = 0; w < wv; ++w) prefix += wsum[w];
    int ex = x + prefix - my;               // exclusive base
    if (tid < BINSZ) {
        bas[tid] = ex;
        int v = (b << BIN_SHIFT) + tid;
        if (v < N) {
            off[v] = s0 + ex;
            dinv[v] = rsqrtf((float)(my + 1));   // +1 self-loop
            if (v == N - 1) off[N] = E;
            // fused gbound (batch sorted)
            int bb = batch[v];
            int prev = (v == 0) ? -1 : batch[v - 1];
            for (int g = prev + 1; g <= bb; ++g) goff[g] = v;
            if (v == N - 1)
                for (int g = bb + 1; g <= G; ++g) goff[g] = N;
        }
    }
    __syncthreads();
    for (int i = s0 + tid; i < s1; i += 256) {
        int p = bkt[i];
        int lo = (p >> 24) & (BINSZ - 1);
        int li = atomicAdd(&cur[lo], 1);
        csr[s0 + bas[lo] + li] = p & 0xFFFFFF;
    }
}

// ---------------- skinny GEMM via MFMA: hs[row] = (X[row] @ W) * dinv[row], fp8 out ----------------
// Wave w computes the 16-row x 16-col tile at cols [16w,16w+16).
// k-map bijection: k = 32s + 8*(lane>>4) + elem, applied to BOTH A and B fragments.
// D layout (HW-verified): col = lane&15, row = 4*(lane>>4) + reg.

__global__ __launch_bounds__(256) void k_gemm(const float* __restrict__ X,
                                              const float* __restrict__ W,
                                              const float* __restrict__ dinv,
                                              unsigned int* __restrict__ Y8, int N) {
    __shared__ float Os[16 * 68];
    int tid = threadIdx.x;
    int lane = tid & 63, w = tid >> 6;
    int m = lane & 15, g = lane >> 4;
    int row0 = blockIdx.x * 16;
    int row = row0 + m;

    // B fragments from global W (row-major [k][n]); L1-hot
    f16x8 B0, B1;
    {
        int n = (w << 4) + m;
        const float* wp = W + (g << 3) * 64 + n;
#pragma unroll
        for (int j = 0; j < 8; ++j) B0[j] = (_Float16)wp[j * 64];
        wp += 32 * 64;
#pragma unroll
        for (int j = 0; j < 8; ++j) B1[j] = (_Float16)wp[j * 64];
    }
    // A fragments straight from global X
    f16x8 A0, A1;
    {
        float4 u0 = make_float4(0.f, 0.f, 0.f, 0.f), u1 = u0, u2 = u0, u3 = u0;
        if (row < N) {
            const float* xp = X + (size_t)row * DIM + (g << 3);
            u0 = *(const float4*)(xp);
            u1 = *(const float4*)(xp + 4);
            u2 = *(const float4*)(xp + 32);
            u3 = *(const float4*)(xp + 36);
        }
        A0[0] = (_Float16)u0.x; A0[1] = (_Float16)u0.y; A0[2] = (_Float16)u0.z; A0[3] = (_Float16)u0.w;
        A0[4] = (_Float16)u1.x; A0[5] = (_Float16)u1.y; A0[6] = (_Float16)u1.z; A0[7] = (_Float16)u1.w;
        A1[0] = (_Float16)u2.x; A1[1] = (_Float16)u2.y; A1[2] = (_Float16)u2.z; A1[3] = (_Float16)u2.w;
        A1[4] = (_Float16)u3.x; A1[5] = (_Float16)u3.y; A1[6] = (_Float16)u3.z; A1[7] = (_Float16)u3.w;
    }
    f32x4 acc = {0.f, 0.f, 0.f, 0.f};
    acc = __builtin_amdgcn_mfma_f32_16x16x32_f16(A0, B0, acc, 0, 0, 0);
    acc = __builtin_amdgcn_mfma_f32_16x16x32_f16(A1, B1, acc, 0, 0, 0);
#pragma unroll
    for (int j = 0; j < 4; ++j)
        Os[((g << 2) + j) * 68 + (w << 4) + m] = acc[j];
    __syncthreads();

    int r = tid >> 4, c = tid & 15;
    int orow = row0 + r;
    if (orow < N) {
        float4 o = *(const float4*)(Os + r * 68 + (c << 2));
        float s = dinv[orow];
        int p = 0;
        p = __builtin_amdgcn_cvt_pk_fp8_f32(o.x * s, o.y * s, p, false);
        p = __builtin_amdgcn_cvt_pk_fp8_f32(o.z * s, o.w * s, p, true);
        Y8[(size_t)orow * 16 + c] = (unsigned int)p;
    } else if (orow == N) {
        Y8[(size_t)orow * 16 + c] = 0u;   // +0 in e4m3 (gather pad row)
    }
}

// ---------------- gather core: 16-lane group per node, 16 edges / 16 loads in flight ----------------
// lane l owns cols 4l..4l+3 (one uint of the fp8 row). Padding slots read row N (zeros,
// single broadcast cacheline). All 16 loads issued before any conversion.

__device__ __forceinline__ float4 gather_rows(const unsigned int* __restrict__ hs8,
                                              const int* __restrict__ csr,
                                              int k0, int k1, int v, int l, int gw4,
                                              int N) {
    float4 a0, a1, a2, a3;
    {
        unsigned int u = hs8[(unsigned)((v << 4) | l)];    // self-loop term
        floatx2 f0 = __builtin_amdgcn_cvt_pk_f32_fp8((int)u, false);
        floatx2 f1 = __builtin_amdgcn_cvt_pk_f32_fp8((int)u, true);
        a0 = make_float4(f0.x, f0.y, f1.x, f1.y);
        a1 = make_float4(0.f, 0.f, 0.f, 0.f);
        a2 = make_float4(0.f, 0.f, 0.f, 0.f);
        a3 = make_float4(0.f, 0.f, 0.f, 0.f);
    }
    for (int kb = k0; kb < k1; kb += 16) {
        int rem = k1 - kb;
        int idx = (l < rem) ? csr[kb + l] : N;
        unsigned uu[16];
#pragma unroll
        for (int t = 0; t < 16; ++t) {
            int s = __shfl(idx, gw4 + t);
            uu[t] = hs8[(unsigned)((s << 4) | l)];
        }
#pragma unroll
        for (int t = 0; t < 16; t += 4) {
            floatx2 q0 = __builtin_amdgcn_cvt_pk_f32_fp8((int)uu[t + 0], false);
            floatx2 q1 = __builtin_amdgcn_cvt_pk_f32_fp8((int)uu[t + 0], true);
            floatx2 q2 = __builtin_amdgcn_cvt_pk_f32_fp8((int)uu[t + 1], false);
            floatx2 q3 = __builtin_amdgcn_cvt_pk_f32_fp8((int)uu[t + 1], true);
            floatx2 q4 = __builtin_amdgcn_cvt_pk_f32_fp8((int)uu[t + 2], false);
            floatx2 q5 = __builtin_amdgcn_cvt_pk_f32_fp8((int)uu[t + 2], true);
            floatx2 q6 = __builtin_amdgcn_cvt_pk_f32_fp8((int)uu[t + 3], false);
            floatx2 q7 = __builtin_amdgcn_cvt_pk_f32_fp8((int)uu[t + 3], true);
            a0.x += q0.x; a0.y += q0.y; a0.z += q1.x; a0.w += q1.y;
            a1.x += q2.x; a1.y += q2.y; a1.z += q3.x; a1.w += q3.y;
            a2.x += q4.x; a2.y += q4.y; a2.z += q5.x; a2.w += q5.y;
            a3.x += q6.x; a3.y += q6.y; a3.z += q7.x; a3.w += q7.y;
        }
    }
    return make_float4(a0.x + a1.x + a2.x + a3.x,
                       a0.y + a1.y + a2.y + a3.y,
                       a0.z + a1.z + a2.z + a3.z,
                       a0.w + a1.w + a2.w + a3.w);
}

// ---------------- fused gather + MFMA GEMM (layer 1 -> hs2 fp8 directly) ----------------
// block = 256 threads = 16 nodes. gathered row relu'd into fp16 LDS tile, MFMA vs W2
// fragments (built from global, no W LDS), fp32 epilogue transpose via Os, fp8 out.

__global__ __launch_bounds__(256) void k_gather_gemm(const unsigned int* __restrict__ hs8,
                                                     const int* __restrict__ csr,
                                                     const int* __restrict__ off,
                                                     const float* __restrict__ dinv,
                                                     const float* __restrict__ bias,
                                                     const float* __restrict__ W,
                                                     unsigned int* __restrict__ hs_out,
                                                     int N) {
    __shared__ _Float16 Xs[16 * 72];
    __shared__ float Os[16 * 68];
    int tid = threadIdx.x;
    int r = tid >> 4, l = tid & 15;
    int lane = tid & 63, w = tid >> 6;
    int m = lane & 15, g = lane >> 4;
    int gw4 = (r & 3) << 4;
    int v = blockIdx.x * 16 + r;

    // B fragments first (global-load latency overlaps the gather)
    f16x8 B0, B1;
    {
        int n = (w << 4) + m;
        const float* wp = W + (g << 3) * 64 + n;
#pragma unroll
        for (int j = 0; j < 8; ++j) B0[j] = (_Float16)wp[j * 64];
        wp += 32 * 64;
#pragma unroll
        for (int j = 0; j < 8; ++j) B1[j] = (_Float16)wp[j * 64];
    }
    if (blockIdx.x == 0 && tid < 16)
        hs_out[(size_t)N * 16 + tid] = 0u;               // zero pad row for gather2

    float dv = 0.f;
    float4 h = make_float4(0.f, 0.f, 0.f, 0.f);
    if (v < N) {
        dv = dinv[v];
        float4 bv = ((const float4*)bias)[l];
        float4 acc = gather_rows(hs8, csr, off[v], off[v + 1], v, l, gw4, N);
        h.x = fmaxf(acc.x * dv + bv.x, 0.f);
        h.y = fmaxf(acc.y * dv + bv.y, 0.f);
        h.z = fmaxf(acc.z * dv + bv.z, 0.f);
        h.w = fmaxf(acc.w * dv + bv.w, 0.f);
    }
    {
        f16x4 hv;
        hv[0] = (_Float16)h.x; hv[1] = (_Float16)h.y;
        hv[2] = (_Float16)h.z; hv[3] = (_Float16)h.w;
        *(f16x4*)(Xs + r * 72 + (l << 2)) = hv;
    }
    __syncthreads();

    f16x8 A0 = *(const f16x8*)(Xs + m * 72 + (g << 3));
    f16x8 A1 = *(const f16x8*)(Xs + m * 72 + 32 + (g << 3));
    f32x4 acc2 = {0.f, 0.f, 0.f, 0.f};
    acc2 = __builtin_amdgcn_mfma_f32_16x16x32_f16(A0, B0, acc2, 0, 0, 0);
    acc2 = __builtin_amdgcn_mfma_f32_16x16x32_f16(A1, B1, acc2, 0, 0, 0);
#pragma unroll
    for (int j = 0; j < 4; ++j)
        Os[((g << 2) + j) * 68 + (w << 4) + m] = acc2[j];
    __syncthreads();

    if (v < N) {
        float4 o = *(const float4*)(Os + r * 68 + (l << 2));
        int p = 0;
        p = __builtin_amdgcn_cvt_pk_fp8_f32(o.x * dv, o.y * dv, p, false);
        p = __builtin_amdgcn_cvt_pk_fp8_f32(o.z * dv, o.w * dv, p, true);
        hs_out[(size_t)v * 16 + l] = (unsigned int)p;
    }
}

// ---------------- fused gather (layer 2) + mean-pool: atomics into out ----------------
// block = 16 nodes; batch sorted -> 1-2 graph segments per block. Each group computes
// relu(acc*dinv+b2)/count[g]; segment leaders reduce over LDS and atomicAdd into out.

__global__ __launch_bounds__(256) void k_gather_pool(const unsigned int* __restrict__ hs8,
                                                     const int* __restrict__ csr,
                                                     const int* __restrict__ off,
                                                     const float* __restrict__ dinv,
                                                     const float* __restrict__ bias,
                                                     const int* __restrict__ batch,
                                                     const int* __restrict__ goff,
                                                     float* __restrict__ out, int N) {
    __shared__ float vals[16][68];
    __shared__ int gid[16];
    int tid = threadIdx.x;
    int r = tid >> 4, l = tid & 15;
    int gw4 = (r & 3) << 4;
    int v = blockIdx.x * 16 + r;

    float4 val = make_float4(0.f, 0.f, 0.f, 0.f);
    int g = -1;
    if (v < N) {
        g = batch[v];
        float dv = dinv[v];
        float4 bv = ((const float4*)bias)[l];
        float4 acc = gather_rows(hs8, csr, off[v], off[v + 1], v, l, gw4, N);
        float inv = 1.0f / (float)(goff[g + 1] - goff[g]);
        val.x = fmaxf(acc.x * dv + bv.x, 0.f) * inv;
        val.y = fmaxf(acc.y * dv + bv.y, 0.f) * inv;
        val.z = fmaxf(acc.z * dv + bv.z, 0.f) * inv;
        val.w = fmaxf(acc.w * dv + bv.w, 0.f) * inv;
    }
    *(float4*)(&vals[r][l << 2]) = val;
    if (l == 0) gid[r] = g;
    __syncthreads();

    if (v < N) {
        bool leader = (r == 0) || (gid[r - 1] != g);
        if (leader) {
            float4 sacc = val;
            for (int rr = r + 1; rr < 16 && gid[rr] == g; ++rr) {
                float4 t = *(const float4*)(&vals[rr][l << 2]);
                sacc.x += t.x; sacc.y += t.y; sacc.z += t.z; sacc.w += t.w;
            }
            float* op = out + (size_t)g * DIM + (l << 2);
            atomicAdd(op + 0, sacc.x);
            atomicAdd(op + 1, sacc.y);
            atomicAdd(op + 2, sacc.z);
            atomicAdd(op + 3, sacc.w);
        }
    }
}

// ---------------- launch ----------------

static inline int cdiv(int a, int b) { return (a + b - 1) / b; }

extern "C" void kernel_launch(void* const* d_in, const int* in_sizes, int n_in,
                              void* d_out, int out_size, void* d_ws, size_t ws_size,
                              hipStream_t stream) {
    const float* x   = (const float*)d_in[0];
    const float* W1  = (const float*)d_in[1];
    const float* b1  = (const float*)d_in[2];
    const float* W2  = (const float*)d_in[3];
    const float* b2  = (const float*)d_in[4];
    const int*   ei  = (const int*)d_in[5];
    const int*   bat = (const int*)d_in[6];

    const int N = in_sizes[0] / DIM;
    const int E = in_sizes[5] / 2;
    const int G = out_size / DIM;
    const int NB = cdiv(N, BINSZ);           // <= MAXBINS
    const int M  = NB * PB;                  // scan length
    const int* src = ei;
    const int* dst = ei + E;
    float* out = (float*)d_out;

    // workspace: hs1 | hs2 | dinv | off | goff | C | S | bsums | csr
    // bkt aliases hs1 (dead before gemm1 writes hs1).
    __half* hs1    = (__half*)d_ws;                         // (N+1)*64 h region (fp8 uses half)
    __half* hs2    = hs1 + (size_t)(N + 1) * DIM;           // (N+1)*64 h region
    float*  dinv   = (float*)(hs2 + (size_t)(N + 1) * DIM); // N f
    int*    off    = (int*)(dinv + N);                      // N+1 i
    int*    goff   = off + (N + 1);                         // G+1 i
    int*    C      = goff + (G + 1);                        // PB*NB i
    int*    S      = C + (size_t)PB * NB;                   // PB*NB i
    int*    bsums  = S + (size_t)PB * NB;                   // up to 1024 i
    int*    csr    = bsums + 1024;                          // E i
    int*    bkt    = (int*)hs1;                             // E i (aliased)

    k_hist<<<PB, 256, 0, stream>>>(dst, C, E, NB);
    int nb2 = cdiv(M, 4096);
    k_scanA<<<nb2, 1024, 0, stream>>>(C, S, bsums, NB, M);
    k_scanB<<<1, 1024, 0, stream>>>(bsums, nb2);
    k_bucket<<<PB, 256, 0, stream>>>(src, dst, S, bsums, bkt, E, NB);
    k_binsort<<<NB, 256, 0, stream>>>(bkt, S, bsums, csr, off, dinv, bat, goff,
                                      out, N, G, E, NB);

    // layer 1 transform: hs1 = (x @ W1) * dinv (fp8 e4m3), MFMA
    k_gemm<<<cdiv(N + 1, 16), 256, 0, stream>>>(x, W1, dinv, (unsigned int*)hs1, N);

    // fused: agg1 = gather(hs1)+b1 ; hs2 = (relu(agg1) @ W2) * dinv (fp8), MFMA
    k_gather_gemm<<<cdiv(N, 16), 256, 0, stream>>>((const unsigned int*)hs1, csr, off,
                                                   dinv, b1, W2, (unsigned int*)hs2, N);

    // fused: layer 2 gather + bias + relu + mean-pool (atomics into out)
    k_gather_pool<<<cdiv(N, 16), 256, 0, stream>>>((const unsigned int*)hs2, csr, off,
                                                   dinv, b2, bat, goff, out, N);
}

// Round 12
// 187.566 us; speedup vs baseline: 1.8624x; 1.0244x over previous
//
#include <hip/hip_runtime.h>
#include <hip/hip_fp16.h>

#define DIM 64
#define BIN_SHIFT 7
#define BINSZ 128      // nodes per bin
#define MAXBINS 1024   // supports N up to 131072
#define PB 512         // edge-slice blocks for hist/bucket (power of 2)
#define PB_LOG 9

typedef __attribute__((ext_vector_type(2))) float floatx2;
typedef __attribute__((ext_vector_type(4))) float f32x4;
typedef __attribute__((ext_vector_type(8))) _Float16 f16x8;
typedef __attribute__((ext_vector_type(4))) _Float16 f16x4;

// XCD-clustered slice id (R11-validated): HW round-robins blocks over 8 XCDs, so
// bid&7 = XCD; this gives XCD x the contiguous slice range [64x, 64x+64) -> adjacent
// bkt/C fragments are written by one XCD's L2 (no cross-XCD false sharing).
__device__ __forceinline__ int slice_of(int bid) {
    return ((bid & 7) << 6) | (bid >> 3);
}

// in-block exclusive prefix of the <=128 raw chunk sums (replaces k_scanB).
// wave 0 only; bp[c] = sum(bsums[0..c)).
__device__ __forceinline__ void scan_bsums(const int* __restrict__ bsums, int nb2,
                                           int* __restrict__ bp) {
    int t = threadIdx.x;
    if (t < 64) {
        int a = (t < nb2) ? bsums[t] : 0;
        int b = (64 + t < nb2) ? bsums[64 + t] : 0;
        int A = a, B = b;
#pragma unroll
        for (int d = 1; d < 64; d <<= 1) {
            int ta = __shfl_up(A, d); if (t >= d) A += ta;
            int tb = __shfl_up(B, d); if (t >= d) B += tb;
        }
        int Ta = __shfl(A, 63);
        bp[t] = A - a;
        bp[64 + t] = Ta + B - b;
    }
}

// ---------------- pass 1: per-block LDS histogram -> C (bin-major, coalesced for scanA) ----------------

__global__ __launch_bounds__(256) void k_hist(const int* __restrict__ dst,
                                              int* __restrict__ C, int E, int NB) {
    __shared__ int h[MAXBINS];
    for (int i = threadIdx.x; i < NB; i += 256) h[i] = 0;
    __syncthreads();
    int blk = slice_of(blockIdx.x);
    int per = (E + PB - 1) / PB;
    int e0 = blk * per;
    int e1 = e0 + per; if (e1 > E) e1 = E;
    for (int e = e0 + (int)threadIdx.x; e < e1; e += 256)
        atomicAdd(&h[dst[e] >> BIN_SHIFT], 1);
    __syncthreads();
    // bin-major write: C[bin*PB + blk]; 16 consecutive blk share a line, all same-XCD
    for (int i = threadIdx.x; i < NB; i += 256)
        C[i * PB + blk] = h[i];
}

// ---------------- pass 2: chunk-local exclusive scan of C (bin-major, coalesced reads) ----------------
// bsums keeps RAW chunk totals; consumers prefix-scan them in-block (scan_bsums).

__global__ __launch_bounds__(1024) void k_scanA(const int* __restrict__ C,
                                                int* __restrict__ S,
                                                int* __restrict__ bsums, int M) {
    __shared__ int sh[1024];
    int tid = threadIdx.x;
    int j0 = blockIdx.x * 4096 + tid * 4;
    int v[4]; int sum = 0;
#pragma unroll
    for (int t = 0; t < 4; ++t) {
        int j = j0 + t;
        int x = (j < M) ? C[j] : 0;          // coalesced: C already bin-major
        v[t] = sum; sum += x;
    }
    sh[tid] = sum;
    __syncthreads();
#pragma unroll
    for (int d = 1; d < 1024; d <<= 1) {
        int t = (tid >= d) ? sh[tid - d] : 0;
        __syncthreads();
        sh[tid] += t;
        __syncthreads();
    }
    int excl = sh[tid] - sum;
#pragma unroll
    for (int t = 0; t < 4; ++t) {
        int j = j0 + t;
        if (j < M) S[j] = excl + v[t];
    }
    if (tid == 1023) bsums[blockIdx.x] = sh[1023];   // raw total (no scanB)
}

// ---------------- pass 3: one-pass bucket scatter, LDS cursors ----------------

__global__ __launch_bounds__(256) void k_bucket(const int* __restrict__ src,
                                                const int* __restrict__ dst,
                                                const int* __restrict__ S,
                                                const int* __restrict__ bsums,
                                                int* __restrict__ bkt, int E, int NB,
                                                int nb2) {
    __shared__ int lcur[MAXBINS];
    __shared__ int bp[128];
    scan_bsums(bsums, nb2, bp);
    int blk = slice_of(blockIdx.x);
    __syncthreads();                         // bp ready
    for (int i = threadIdx.x; i < NB; i += 256) {
        int j = i * PB + blk;
        lcur[i] = S[j] + bp[j >> 12];
    }
    __syncthreads();
    int per = (E + PB - 1) / PB;
    int e0 = blk * per;
    int e1 = e0 + per; if (e1 > E) e1 = E;
    for (int e = e0 + (int)threadIdx.x; e < e1; e += 256) {
        int d = dst[e];
        int pos = atomicAdd(&lcur[d >> BIN_SHIFT], 1);
        bkt[pos] = src[e] | ((d & (BINSZ - 1)) << 24);
    }
}

// ---------------- pass 4: per-bin counting sort -> csr, off, dinv; + gbound; + zero out ----------------

__global__ __launch_bounds__(256) void k_binsort(const int* __restrict__ bkt,
                                                 const int* __restrict__ S,
                                                 const int* __restrict__ bsums,
                                                 int* __restrict__ csr,
                                                 int* __restrict__ off,
                                                 float* __restrict__ dinv,
                                                 const int* __restrict__ batch,
                                                 int* __restrict__ goff,
                                                 float* __restrict__ outz,
                                                 int N, int G, int E, int NB, int nb2) {
    __shared__ int cnt[BINSZ], bas[BINSZ], cur[BINSZ];
    __shared__ int wsum[4];
    __shared__ int bp[128];
    int tid = threadIdx.x;
    int b = blockIdx.x;
    scan_bsums(bsums, nb2, bp);
    if (tid < BINSZ) { cnt[tid] = 0; cur[tid] = 0; }
    // zero the pooled output (k_gather_pool accumulates via atomics)
    for (int i = b * 256 + tid; i < G * DIM; i += NB * 256) outz[i] = 0.f;
    __syncthreads();                         // bp + cnt/cur ready
    int j0 = b << PB_LOG;
    int s0 = S[j0] + bp[j0 >> 12];
    int s1 = E;
    if (b + 1 < NB) { int j1 = (b + 1) << PB_LOG; s1 = S[j1] + bp[j1 >> 12]; }
    for (int i = s0 + tid; i < s1; i += 256)
        atomicAdd(&cnt[(bkt[i] >> 24) & (BINSZ - 1)], 1);
    __syncthreads();
    int my = (tid < BINSZ) ? cnt[tid] : 0;
    int lane = tid & 63, wv = tid >> 6;
    int x = my;
#pragma unroll
    for (int d = 1; d < 64; d <<= 1) {
        int t = __shfl_up(x, d);
        if (lane >= d) x += t;
    }
    if (lane == 63) wsum[wv] = x;
    __syncthreads();
    int prefix = 0;
    for (int w = 0; w < wv; ++w) prefix += wsum[w];
    int ex = x + prefix - my;               // exclusive base
    if (tid < BINSZ) {
        bas[tid] = ex;
        int v = (b << BIN_SHIFT) + tid;
        if (v < N) {
            off[v] = s0 + ex;
            dinv[v] = rsqrtf((float)(my + 1));   // +1 self-loop
            if (v == N - 1) off[N] = E;
            // fused gbound (batch sorted)
            int bb = batch[v];
            int prev = (v == 0) ? -1 : batch[v - 1];
            for (int g = prev + 1; g <= bb; ++g) goff[g] = v;
            if (v == N - 1)
                for (int g = bb + 1; g <= G; ++g) goff[g] = N;
        }
    }
    __syncthreads();
    for (int i = s0 + tid; i < s1; i += 256) {
        int p = bkt[i];
        int lo = (p >> 24) & (BINSZ - 1);
        int li = atomicAdd(&cur[lo], 1);
        csr[s0 + bas[lo] + li] = p & 0xFFFFFF;
    }
}

// ---------------- skinny GEMM via MFMA: hs[row] = (X[row] @ W) * dinv[row], fp8 out ----------------
// Wave w computes the 16-row x 16-col tile at cols [16w,16w+16).
// k-map bijection: k = 32s + 8*(lane>>4) + elem, applied to BOTH A and B fragments.
// D layout (HW-verified): col = lane&15, row = 4*(lane>>4) + reg.

__global__ __launch_bounds__(256) void k_gemm(const float* __restrict__ X,
                                              const float* __restrict__ W,
                                              const float* __restrict__ dinv,
                                              unsigned int* __restrict__ Y8, int N) {
    __shared__ float Os[16 * 68];
    int tid = threadIdx.x;
    int lane = tid & 63, w = tid >> 6;
    int m = lane & 15, g = lane >> 4;
    int row0 = blockIdx.x * 16;
    int row = row0 + m;

    // B fragments from global W (row-major [k][n]); L1-hot
    f16x8 B0, B1;
    {
        int n = (w << 4) + m;
        const float* wp = W + (g << 3) * 64 + n;
#pragma unroll
        for (int j = 0; j < 8; ++j) B0[j] = (_Float16)wp[j * 64];
        wp += 32 * 64;
#pragma unroll
        for (int j = 0; j < 8; ++j) B1[j] = (_Float16)wp[j * 64];
    }
    // A fragments straight from global X
    f16x8 A0, A1;
    {
        float4 u0 = make_float4(0.f, 0.f, 0.f, 0.f), u1 = u0, u2 = u0, u3 = u0;
        if (row < N) {
            const float* xp = X + (size_t)row * DIM + (g << 3);
            u0 = *(const float4*)(xp);
            u1 = *(const float4*)(xp + 4);
            u2 = *(const float4*)(xp + 32);
            u3 = *(const float4*)(xp + 36);
        }
        A0[0] = (_Float16)u0.x; A0[1] = (_Float16)u0.y; A0[2] = (_Float16)u0.z; A0[3] = (_Float16)u0.w;
        A0[4] = (_Float16)u1.x; A0[5] = (_Float16)u1.y; A0[6] = (_Float16)u1.z; A0[7] = (_Float16)u1.w;
        A1[0] = (_Float16)u2.x; A1[1] = (_Float16)u2.y; A1[2] = (_Float16)u2.z; A1[3] = (_Float16)u2.w;
        A1[4] = (_Float16)u3.x; A1[5] = (_Float16)u3.y; A1[6] = (_Float16)u3.z; A1[7] = (_Float16)u3.w;
    }
    f32x4 acc = {0.f, 0.f, 0.f, 0.f};
    acc = __builtin_amdgcn_mfma_f32_16x16x32_f16(A0, B0, acc, 0, 0, 0);
    acc = __builtin_amdgcn_mfma_f32_16x16x32_f16(A1, B1, acc, 0, 0, 0);
#pragma unroll
    for (int j = 0; j < 4; ++j)
        Os[((g << 2) + j) * 68 + (w << 4) + m] = acc[j];
    __syncthreads();

    int r = tid >> 4, c = tid & 15;
    int orow = row0 + r;
    if (orow < N) {
        float4 o = *(const float4*)(Os + r * 68 + (c << 2));
        float s = dinv[orow];
        int p = 0;
        p = __builtin_amdgcn_cvt_pk_fp8_f32(o.x * s, o.y * s, p, false);
        p = __builtin_amdgcn_cvt_pk_fp8_f32(o.z * s, o.w * s, p, true);
        Y8[(size_t)orow * 16 + c] = (unsigned int)p;
    } else if (orow == N) {
        Y8[(size_t)orow * 16 + c] = 0u;   // +0 in e4m3 (gather pad row)
    }
}

// ---------------- gather core: 16-lane group per node, 16 edges / 16 loads in flight ----------------
// lane l owns cols 4l..4l+3 (one uint of the fp8 row). Padding slots read row N (zeros,
// single broadcast cacheline). All 16 loads issued before any conversion.

__device__ __forceinline__ float4 gather_rows(const unsigned int* __restrict__ hs8,
                                              const int* __restrict__ csr,
                                              int k0, int k1, int v, int l, int gw4,
                                              int N) {
    float4 a0, a1, a2, a3;
    {
        unsigned int u = hs8[(unsigned)((v << 4) | l)];    // self-loop term
        floatx2 f0 = __builtin_amdgcn_cvt_pk_f32_fp8((int)u, false);
        floatx2 f1 = __builtin_amdgcn_cvt_pk_f32_fp8((int)u, true);
        a0 = make_float4(f0.x, f0.y, f1.x, f1.y);
        a1 = make_float4(0.f, 0.f, 0.f, 0.f);
        a2 = make_float4(0.f, 0.f, 0.f, 0.f);
        a3 = make_float4(0.f, 0.f, 0.f, 0.f);
    }
    for (int kb = k0; kb < k1; kb += 16) {
        int rem = k1 - kb;
        int idx = (l < rem) ? csr[kb + l] : N;
        unsigned uu[16];
#pragma unroll
        for (int t = 0; t < 16; ++t) {
            int s = __shfl(idx, gw4 + t);
            uu[t] = hs8[(unsigned)((s << 4) | l)];
        }
#pragma unroll
        for (int t = 0; t < 16; t += 4) {
            floatx2 q0 = __builtin_amdgcn_cvt_pk_f32_fp8((int)uu[t + 0], false);
            floatx2 q1 = __builtin_amdgcn_cvt_pk_f32_fp8((int)uu[t + 0], true);
            floatx2 q2 = __builtin_amdgcn_cvt_pk_f32_fp8((int)uu[t + 1], false);
            floatx2 q3 = __builtin_amdgcn_cvt_pk_f32_fp8((int)uu[t + 1], true);
            floatx2 q4 = __builtin_amdgcn_cvt_pk_f32_fp8((int)uu[t + 2], false);
            floatx2 q5 = __builtin_amdgcn_cvt_pk_f32_fp8((int)uu[t + 2], true);
            floatx2 q6 = __builtin_amdgcn_cvt_pk_f32_fp8((int)uu[t + 3], false);
            floatx2 q7 = __builtin_amdgcn_cvt_pk_f32_fp8((int)uu[t + 3], true);
            a0.x += q0.x; a0.y += q0.y; a0.z += q1.x; a0.w += q1.y;
            a1.x += q2.x; a1.y += q2.y; a1.z += q3.x; a1.w += q3.y;
            a2.x += q4.x; a2.y += q4.y; a2.z += q5.x; a2.w += q5.y;
            a3.x += q6.x; a3.y += q6.y; a3.z += q7.x; a3.w += q7.y;
        }
    }
    return make_float4(a0.x + a1.x + a2.x + a3.x,
                       a0.y + a1.y + a2.y + a3.y,
                       a0.z + a1.z + a2.z + a3.z,
                       a0.w + a1.w + a2.w + a3.w);
}

// ---------------- fused gather + MFMA GEMM (layer 1 -> hs2 fp8 directly) ----------------
// block = 256 threads = 16 nodes. gathered row relu'd into fp16 LDS tile, MFMA vs W2
// fragments (built from global, no W LDS), fp32 epilogue transpose via Os, fp8 out.

__global__ __launch_bounds__(256) void k_gather_gemm(const unsigned int* __restrict__ hs8,
                                                     const int* __restrict__ csr,
                                                     const int* __restrict__ off,
                                                     const float* __restrict__ dinv,
                                                     const float* __restrict__ bias,
                                                     const float* __restrict__ W,
                                                     unsigned int* __restrict__ hs_out,
                                                     int N) {
    __shared__ _Float16 Xs[16 * 72];
    __shared__ float Os[16 * 68];
    int tid = threadIdx.x;
    int r = tid >> 4, l = tid & 15;
    int lane = tid & 63, w = tid >> 6;
    int m = lane & 15, g = lane >> 4;
    int gw4 = (r & 3) << 4;
    int v = blockIdx.x * 16 + r;

    // B fragments first (global-load latency overlaps the gather)
    f16x8 B0, B1;
    {
        int n = (w << 4) + m;
        const float* wp = W + (g << 3) * 64 + n;
#pragma unroll
        for (int j = 0; j < 8; ++j) B0[j] = (_Float16)wp[j * 64];
        wp += 32 * 64;
#pragma unroll
        for (int j = 0; j < 8; ++j) B1[j] = (_Float16)wp[j * 64];
    }
    if (blockIdx.x == 0 && tid < 16)
        hs_out[(size_t)N * 16 + tid] = 0u;               // zero pad row for gather2

    float dv = 0.f;
    float4 h = make_float4(0.f, 0.f, 0.f, 0.f);
    if (v < N) {
        dv = dinv[v];
        float4 bv = ((const float4*)bias)[l];
        float4 acc = gather_rows(hs8, csr, off[v], off[v + 1], v, l, gw4, N);
        h.x = fmaxf(acc.x * dv + bv.x, 0.f);
        h.y = fmaxf(acc.y * dv + bv.y, 0.f);
        h.z = fmaxf(acc.z * dv + bv.z, 0.f);
        h.w = fmaxf(acc.w * dv + bv.w, 0.f);
    }
    {
        f16x4 hv;
        hv[0] = (_Float16)h.x; hv[1] = (_Float16)h.y;
        hv[2] = (_Float16)h.z; hv[3] = (_Float16)h.w;
        *(f16x4*)(Xs + r * 72 + (l << 2)) = hv;
    }
    __syncthreads();

    f16x8 A0 = *(const f16x8*)(Xs + m * 72 + (g << 3));
    f16x8 A1 = *(const f16x8*)(Xs + m * 72 + 32 + (g << 3));
    f32x4 acc2 = {0.f, 0.f, 0.f, 0.f};
    acc2 = __builtin_amdgcn_mfma_f32_16x16x32_f16(A0, B0, acc2, 0, 0, 0);
    acc2 = __builtin_amdgcn_mfma_f32_16x16x32_f16(A1, B1, acc2, 0, 0, 0);
#pragma unroll
    for (int j = 0; j < 4; ++j)
        Os[((g << 2) + j) * 68 + (w << 4) + m] = acc2[j];
    __syncthreads();

    if (v < N) {
        float4 o = *(const float4*)(Os + r * 68 + (l << 2));
        int p = 0;
        p = __builtin_amdgcn_cvt_pk_fp8_f32(o.x * dv, o.y * dv, p, false);
        p = __builtin_amdgcn_cvt_pk_fp8_f32(o.z * dv, o.w * dv, p, true);
        hs_out[(size_t)v * 16 + l] = (unsigned int)p;
    }
}

// ---------------- fused gather (layer 2) + mean-pool: atomics into out ----------------
// block = 16 nodes; batch sorted -> 1-2 graph segments per block. Each group computes
// relu(acc*dinv+b2)/count[g]; segment leaders reduce over LDS and atomicAdd into out.

__global__ __launch_bounds__(256) void k_gather_pool(const unsigned int* __restrict__ hs8,
                                                     const int* __restrict__ csr,
                                                     const int* __restrict__ off,
                                                     const float* __restrict__ dinv,
                                                     const float* __restrict__ bias,
                                                     const int* __restrict__ batch,
                                                     const int* __restrict__ goff,
                                                     float* __restrict__ out, int N) {
    __shared__ float vals[16][68];
    __shared__ int gid[16];
    int tid = threadIdx.x;
    int r = tid >> 4, l = tid & 15;
    int gw4 = (r & 3) << 4;
    int v = blockIdx.x * 16 + r;

    float4 val = make_float4(0.f, 0.f, 0.f, 0.f);
    int g = -1;
    if (v < N) {
        g = batch[v];
        float dv = dinv[v];
        float4 bv = ((const float4*)bias)[l];
        float4 acc = gather_rows(hs8, csr, off[v], off[v + 1], v, l, gw4, N);
        float inv = 1.0f / (float)(goff[g + 1] - goff[g]);
        val.x = fmaxf(acc.x * dv + bv.x, 0.f) * inv;
        val.y = fmaxf(acc.y * dv + bv.y, 0.f) * inv;
        val.z = fmaxf(acc.z * dv + bv.z, 0.f) * inv;
        val.w = fmaxf(acc.w * dv + bv.w, 0.f) * inv;
    }
    *(float4*)(&vals[r][l << 2]) = val;
    if (l == 0) gid[r] = g;
    __syncthreads();

    if (v < N) {
        bool leader = (r == 0) || (gid[r - 1] != g);
        if (leader) {
            float4 sacc = val;
            for (int rr = r + 1; rr < 16 && gid[rr] == g; ++rr) {
                float4 t = *(const float4*)(&vals[rr][l << 2]);
                sacc.x += t.x; sacc.y += t.y; sacc.z += t.z; sacc.w += t.w;
            }
            float* op = out + (size_t)g * DIM + (l << 2);
            atomicAdd(op + 0, sacc.x);
            atomicAdd(op + 1, sacc.y);
            atomicAdd(op + 2, sacc.z);
            atomicAdd(op + 3, sacc.w);
        }
    }
}

// ---------------- launch ----------------

static inline int cdiv(int a, int b) { return (a + b - 1) / b; }

extern "C" void kernel_launch(void* const* d_in, const int* in_sizes, int n_in,
                              void* d_out, int out_size, void* d_ws, size_t ws_size,
                              hipStream_t stream) {
    const float* x   = (const float*)d_in[0];
    const float* W1  = (const float*)d_in[1];
    const float* b1  = (const float*)d_in[2];
    const float* W2  = (const float*)d_in[3];
    const float* b2  = (const float*)d_in[4];
    const int*   ei  = (const int*)d_in[5];
    const int*   bat = (const int*)d_in[6];

    const int N = in_sizes[0] / DIM;
    const int E = in_sizes[5] / 2;
    const int G = out_size / DIM;
    const int NB = cdiv(N, BINSZ);           // <= MAXBINS
    const int M  = NB * PB;                  // scan length
    const int* src = ei;
    const int* dst = ei + E;
    float* out = (float*)d_out;

    // workspace: hs1 | hs2 | dinv | off | goff | C | S | bsums | csr
    // bkt aliases hs1 (dead before gemm1 writes hs1).
    __half* hs1    = (__half*)d_ws;                         // (N+1)*64 h region (fp8 uses half)
    __half* hs2    = hs1 + (size_t)(N + 1) * DIM;           // (N+1)*64 h region
    float*  dinv   = (float*)(hs2 + (size_t)(N + 1) * DIM); // N f
    int*    off    = (int*)(dinv + N);                      // N+1 i
    int*    goff   = off + (N + 1);                         // G+1 i
    int*    C      = goff + (G + 1);                        // PB*NB i (bin-major)
    int*    S      = C + (size_t)PB * NB;                   // PB*NB i
    int*    bsums  = S + (size_t)PB * NB;                   // up to 128 i (raw totals)
    int*    csr    = bsums + 1024;                          // E i
    int*    bkt    = (int*)hs1;                             // E i (aliased)

    int nb2 = cdiv(M, 4096);                 // <= 128 (fits scan_bsums)

    k_hist<<<PB, 256, 0, stream>>>(dst, C, E, NB);
    k_scanA<<<nb2, 1024, 0, stream>>>(C, S, bsums, M);
    k_bucket<<<PB, 256, 0, stream>>>(src, dst, S, bsums, bkt, E, NB, nb2);
    k_binsort<<<NB, 256, 0, stream>>>(bkt, S, bsums, csr, off, dinv, bat, goff,
                                      out, N, G, E, NB, nb2);

    // layer 1 transform: hs1 = (x @ W1) * dinv (fp8 e4m3), MFMA
    k_gemm<<<cdiv(N + 1, 16), 256, 0, stream>>>(x, W1, dinv, (unsigned int*)hs1, N);

    // fused: agg1 = gather(hs1)+b1 ; hs2 = (relu(agg1) @ W2) * dinv (fp8), MFMA
    k_gather_gemm<<<cdiv(N, 16), 256, 0, stream>>>((const unsigned int*)hs1, csr, off,
                                                   dinv, b1, W2, (unsigned int*)hs2, N);

    // fused: layer 2 gather + bias + relu + mean-pool (atomics into out)
    k_gather_pool<<<cdiv(N, 16), 256, 0, stream>>>((const unsigned int*)hs2, csr, off,
                                                   dinv, b2, bat, goff, out, N);
}